// Round 12
// baseline (176.268 us; speedup 1.0000x reference)
//
#include <hip/hip_runtime.h>

typedef __attribute__((ext_vector_type(8))) short bf16x8;
typedef __attribute__((ext_vector_type(4))) float f32x4;
typedef __attribute__((ext_vector_type(16))) float f32x16;

#define B_  2
#define S_  2048
#define DM  512
#define KD  256
#define HD  32
#define NH  8

__device__ __forceinline__ float bf2f(ushort u) {
    return __uint_as_float(((uint)u) << 16);
}
__device__ __forceinline__ ushort f2bf(float f) {
    uint x = __float_as_uint(f);
    return (ushort)((x + 0x7fffu + ((x >> 16) & 1u)) >> 16);  // RNE
}
// gfx950 packed f32->bf16 (RNE), 1 instr per 2 elements
__device__ __forceinline__ uint cvt_pk_bf16(float lo, float hi) {
    uint r;
    asm("v_cvt_pk_bf16_f32 %0, %1, %2" : "=v"(r) : "v"(lo), "v"(hi));
    return r;
}
#define MFMA __builtin_amdgcn_mfma_f32_16x16x32_bf16
#define MFMA32 __builtin_amdgcn_mfma_f32_32x32x16_bf16

__device__ __forceinline__ int detect_isbf(const ushort* __restrict__ q)
{
    int lane = threadIdx.x & 63;
    int e = (q[lane] >> 7) & 0xFF;
    unsigned long long m = __ballot(e >= 100 && e <= 133);
    return __popcll(m) >= 58;
}

// ---- W transposes + biases; output in PACKED fragment layout [n/16][k/8][16][8]
__global__ __launch_bounds__(256) void transpose_w(
    const void* __restrict__ Wq, const void* __restrict__ Wk, const void* __restrict__ Wv,
    const void* __restrict__ Wo,
    const void* __restrict__ bq, const void* __restrict__ bk,
    const void* __restrict__ bv, const void* __restrict__ bo,
    const ushort* __restrict__ qsrc,
    ushort* __restrict__ Wt, ushort* __restrict__ Wot, float* __restrict__ biasf)
{
    int isbf = detect_isbf(qsrc);
    int bid = blockIdx.x;
    if (bid >= 512) {
        for (int i = threadIdx.x; i < 1280; i += 256) {
            const void* bp; int off;
            if (i < 256)      { bp = bq; off = i; }
            else if (i < 512) { bp = bk; off = i - 256; }
            else if (i < 768) { bp = bv; off = i - 512; }
            else              { bp = bo; off = i - 768; }
            biasf[i] = isbf ? bf2f(((const ushort*)bp)[off]) : ((const float*)bp)[off];
        }
        return;
    }
    const void* W; int R, C; ushort* T;
    int m = bid >> 7, tix = bid & 127;
    if (m < 3) { W = (m == 0) ? Wq : (m == 1) ? Wk : Wv; R = 512; C = 256; T = Wt + m * 131072; }
    else       { W = Wo; R = 256; C = 512; T = Wot; }
    int tilesPerRow = C >> 5;
    int r0 = (tix / tilesPerRow) * 32, c0 = (tix % tilesPerRow) * 32;
    __shared__ float lds[32][33];
    int t = threadIdx.x;
    int rr = t >> 3, cc = (t & 7) * 4;
    if (isbf) {
        const ushort* Ws = (const ushort*)W;
        #pragma unroll
        for (int j = 0; j < 4; ++j) lds[rr][cc + j] = bf2f(Ws[(size_t)(r0 + rr) * C + c0 + cc + j]);
    } else {
        float4 v = *(const float4*)((const float*)W + (size_t)(r0 + rr) * C + c0 + cc);
        lds[rr][cc + 0] = v.x; lds[rr][cc + 1] = v.y; lds[rr][cc + 2] = v.z; lds[rr][cc + 3] = v.w;
    }
    __syncthreads();
    ushort4 o;
    o.x = f2bf(lds[cc + 0][rr]); o.y = f2bf(lds[cc + 1][rr]);
    o.z = f2bf(lds[cc + 2][rr]); o.w = f2bf(lds[cc + 3][rr]);
    int n = c0 + rr, k = r0 + cc;
    *(ushort4*)(T + ((((size_t)(n >> 4) * (R >> 3) + (k >> 3)) * 16 + (n & 15)) << 3) + (k & 7)) = o;
}

// ---- QKV GEMM. R15: 32-row m-tiles (grid 128x3) + DEPTH-2 software pipeline
// (3-stage circular frag buffers, fully unrolled k-loop so all stage indices
// are compile-time -> no scratch). 8 MFMA/step vs 4, two steps of A/B loads in
// flight -> per-step wait ~ L/2 instead of L. B re-reads from L2 halved.
// V still written in MFMA32 B-frag packed layout.
__global__ __launch_bounds__(256) void qkv_gemm(
    const void* __restrict__ Q, const void* __restrict__ K, const void* __restrict__ V,
    const ushort* __restrict__ Wt, const float* __restrict__ biasf,
    ushort* __restrict__ qh, ushort* __restrict__ kh, ushort* __restrict__ vT)
{
    int isbf = detect_isbf((const ushort*)Q);
    int y = blockIdx.y;
    const void* X = (y == 0) ? Q : (y == 1) ? K : V;
    int wave = threadIdx.x >> 6, lane = threadIdx.x & 63;
    int l16 = lane & 15, quad = lane >> 4;
    int m0 = blockIdx.x * 32;           // grid.x = 128
    int n0 = wave * 64;
    const ushort* W = Wt + (size_t)y * (256 * 512);

    auto loadA = [&](int ks, bf16x8* a) {
        #pragma unroll
        for (int i = 0; i < 2; ++i) {
            if (isbf) {
                a[i] = *(const bf16x8*)((const ushort*)X + (size_t)(m0 + 16 * i + l16) * 512 + ks + quad * 8);
            } else {
                const float* p = (const float*)X + (size_t)(m0 + 16 * i + l16) * 512 + ks + quad * 8;
                float4 f0 = *(const float4*)p, f1 = *(const float4*)(p + 4);
                union { uint u[4]; bf16x8 v; } cv;
                cv.u[0] = cvt_pk_bf16(f0.x, f0.y);
                cv.u[1] = cvt_pk_bf16(f0.z, f0.w);
                cv.u[2] = cvt_pk_bf16(f1.x, f1.y);
                cv.u[3] = cvt_pk_bf16(f1.z, f1.w);
                a[i] = cv.v;
            }
        }
    };
    auto loadB = [&](int ks, bf16x8* b) {
        #pragma unroll
        for (int j = 0; j < 4; ++j)
            b[j] = *(const bf16x8*)(W + (((size_t)((n0 >> 4) + j) * 64 + (ks >> 3) + quad) * 16 + l16) * 8);
    };

    f32x4 acc[2][4] = {};
    bf16x8 Aq[3][2], Bq[3][4];
    loadA(0, Aq[0]); loadB(0, Bq[0]);
    loadA(32, Aq[1]); loadB(32, Bq[1]);
    #pragma unroll
    for (int i = 0; i < 16; ++i) {
        int cur = i % 3, nxt = (i + 2) % 3;
        if (i + 2 < 16) { loadA((i + 2) * 32, Aq[nxt]); loadB((i + 2) * 32, Bq[nxt]); }
        #pragma unroll
        for (int ii = 0; ii < 2; ++ii)
            #pragma unroll
            for (int j = 0; j < 4; ++j)
                acc[ii][j] = MFMA(Aq[cur][ii], Bq[cur][j], acc[ii][j], 0, 0, 0);
    }
    if (y < 2) {
        ushort* out = (y == 0) ? qh : kh;
        #pragma unroll
        for (int ii = 0; ii < 2; ++ii) {
            #pragma unroll
            for (int j = 0; j < 4; ++j) {
                int n = n0 + 16 * j + l16;
                float bs = biasf[y * 256 + n];
                int h = n >> 5, d = n & 31;
                #pragma unroll
                for (int r = 0; r < 4; ++r) {
                    int rg = m0 + 16 * ii + quad * 4 + r;
                    int bb = rg >> 11, ss = rg & 2047;
                    out[((((size_t)bb * NH + h) * S_ + ss) << 5) + d] = f2bf(acc[ii][j][r] + bs);
                }
            }
        }
    } else {
        #pragma unroll
        for (int ii = 0; ii < 2; ++ii) {
            int rg0 = m0 + 16 * ii + quad * 4;
            int bb = rg0 >> 11;
            int tt = (rg0 & 2047) >> 4;
            int sb = quad >> 1;
            int jb = (quad & 1) * 4;
            #pragma unroll
            for (int j = 0; j < 4; ++j) {
                int n = n0 + 16 * j + l16;
                float bs = biasf[2 * 256 + n];
                int h = n >> 5, d = n & 31;
                ushort4 o;
                o.x = f2bf(acc[ii][j][0] + bs); o.y = f2bf(acc[ii][j][1] + bs);
                o.z = f2bf(acc[ii][j][2] + bs); o.w = f2bf(acc[ii][j][3] + bs);
                *(ushort4*)(vT + ((((size_t)(bb * NH + h) * 128 + tt) * 64 + d + 32 * sb) << 3) + jb) = o;
            }
        }
    }
}

// ---- attention (R10 head-grouped version, unchanged): 512 threads = 8 heads,
// mask staged once per block (L3 rebroadcast eliminated), in-register softmax.
__global__ __launch_bounds__(512) void attn(
    const ushort* __restrict__ qh, const ushort* __restrict__ kh,
    const ushort* __restrict__ vT, const void* __restrict__ maskp,
    float* __restrict__ pO, float* __restrict__ pl, int chsh)
{
    __shared__ float ldsM[2][32][33];   // 8.4 KB
    int isbf;
    {
        int lane = threadIdx.x & 63;
        ushort u = ((const ushort*)maskp)[lane];
        int e = (u >> 7) & 0xFF;
        unsigned long long m = __ballot(e >= 100 && e <= 133);
        isbf = __popcll(m) >= 58;
    }
    int tid = threadIdx.x;
    int wave = tid >> 6, lane = tid & 63;
    int l31 = lane & 31, hi = lane >> 5;
    int CH = 1 << chsh;
    int bid = blockIdx.x;                    // grid = 128 << chsh
    int chunk = bid & (CH - 1);
    int qt32 = (bid >> chsh) & 63;
    int b = bid >> (chsh + 6);
    int h = wave;                            // one head per wave
    int bh = b * NH + h;
    int q0 = qt32 * 32;
    int klen = 2048 >> chsh;
    int kbase = chunk * klen;
    int NT = klen >> 5;                      // 32-k substeps

    const ushort* qb = qh + (size_t)bh * S_ * HD;
    const ushort* kb = kh + (size_t)bh * S_ * HD;
    const ushort* vbp = vT + (size_t)bh * 65536;     // packed [s/16][lane][8]
    const ushort* mbb = (const ushort*)maskp + (size_t)b * S_ * S_;
    const float*  mbf = (const float*)maskp  + (size_t)b * S_ * S_;

    bf16x8 bq0 = *(const bf16x8*)(qb + (size_t)(q0 + l31) * HD + hi * 8);
    bf16x8 bq1 = *(const bf16x8*)(qb + (size_t)(q0 + l31) * HD + 16 + hi * 8);

    f32x16 O = {0,0,0,0,0,0,0,0,0,0,0,0,0,0,0,0};
    const f32x16 Z = {0,0,0,0,0,0,0,0,0,0,0,0,0,0,0,0};
    float lsum = 0.0f;

    // mask staging: 512 threads, one float2 each: row=tid>>4, col=(tid&15)*2
    int srow = tid >> 4, scol = (tid & 15) * 2;
    float2 g;

    auto loadMg = [&](int k0) {
        if (isbf) {
            ushort2 u = *(const ushort2*)(mbb + (size_t)(q0 + srow) * S_ + k0 + scol);
            g.x = bf2f(u.x); g.y = bf2f(u.y);
        } else {
            g = *(const float2*)(mbf + (size_t)(q0 + srow) * S_ + k0 + scol);
        }
    };
    auto writeM = [&](int buf) {
        ldsM[buf][srow][scol]     = g.x;
        ldsM[buf][srow][scol + 1] = g.y;
    };
    auto loadK = [&](int k0, bf16x8* K2) {
        K2[0] = *(const bf16x8*)(kb + (size_t)(k0 + l31) * HD + hi * 8);
        K2[1] = *(const bf16x8*)(kb + (size_t)(k0 + l31) * HD + 16 + hi * 8);
    };
    auto loadV = [&](int k0, bf16x8* V2) {
        int t0 = k0 >> 4;
        V2[0] = *(const bf16x8*)(vbp + (((size_t)t0 * 64 + lane) << 3));
        V2[1] = *(const bf16x8*)(vbp + (((size_t)(t0 + 1) * 64 + lane) << 3));
    };

    auto sub = [&](int buf, bf16x8* Kc, bf16x8* Vc, bf16x8* Kn, bf16x8* Vn, int t) {
        float Mreg[16];
        #pragma unroll
        for (int r = 0; r < 16; ++r)
            Mreg[r] = ldsM[buf][l31][(r & 3) + ((r >> 2) << 3) + (hi << 2)];
        int ktn = kbase + ((t + 1 < NT) ? (t + 1) : (NT - 1)) * 32;
        loadK(ktn, Kn); loadV(ktn, Vn);
        f32x16 S = MFMA32(Kc[0], bq0, Z, 0, 0, 0);
        S = MFMA32(Kc[1], bq1, S, 0, 0, 0);
        writeM(buf ^ 1);
        loadMg(kbase + ((t + 2 < NT) ? (t + 2) : (NT - 1)) * 32);
        float p[16];
        #pragma unroll
        for (int r = 0; r < 16; ++r) {
            p[r] = __expf(fmaf(S[r], 0.0625f, Mreg[r]));
            lsum += p[r];
        }
        union { uint u[4]; bf16x8 v; } pa0, pa1;
        {
            uint u0 = cvt_pk_bf16(p[0], p[1]),  w0 = cvt_pk_bf16(p[4], p[5]);
            uint u1 = cvt_pk_bf16(p[2], p[3]),  w1 = cvt_pk_bf16(p[6], p[7]);
            asm volatile("v_permlane32_swap_b32 %0, %1" : "+v"(u0), "+v"(w0));
            asm volatile("v_permlane32_swap_b32 %0, %1" : "+v"(u1), "+v"(w1));
            pa0.u[0] = u0; pa0.u[1] = u1; pa0.u[2] = w0; pa0.u[3] = w1;
            uint u2 = cvt_pk_bf16(p[8], p[9]),   w2 = cvt_pk_bf16(p[12], p[13]);
            uint u3 = cvt_pk_bf16(p[10], p[11]), w3 = cvt_pk_bf16(p[14], p[15]);
            asm volatile("v_permlane32_swap_b32 %0, %1" : "+v"(u2), "+v"(w2));
            asm volatile("v_permlane32_swap_b32 %0, %1" : "+v"(u3), "+v"(w3));
            pa1.u[0] = u2; pa1.u[1] = u3; pa1.u[2] = w2; pa1.u[3] = w3;
        }
        O = MFMA32(pa0.v, Vc[0], O, 0, 0, 0);
        O = MFMA32(pa1.v, Vc[1], O, 0, 0, 0);
        __syncthreads();   // tile t fully read; tile t+1 writes visible
    };

    bf16x8 KA[2], VA[2], KB[2], VB[2];
    loadK(kbase, KA); loadV(kbase, VA);
    loadMg(kbase); writeM(0);
    loadMg(kbase + ((1 < NT) ? 32 : 0));
    __syncthreads();
    for (int t = 0; t < NT; t += 2) {
        sub(0, KA, VA, KB, VB, t);
        sub(1, KB, VB, KA, VA, t + 1);
    }

    float tot = lsum + __shfl_xor(lsum, 32, 64);
    int wid16_0 = (((bh << 7) + qt32 * 2 + 0) << chsh) + chunk;
    int wid16_1 = (((bh << 7) + qt32 * 2 + 1) << chsh) + chunk;
    if (lane < 32) {
        int q = l31;
        int w16 = (q < 16) ? wid16_0 : wid16_1;
        pl[w16 * 16 + (q & 15)] = tot;
    }
    #pragma unroll
    for (int r = 0; r < 16; ++r) {
        int q = (r & 3) + ((r >> 2) << 3) + (hi << 2);
        int w16 = (q < 16) ? wid16_0 : wid16_1;
        pO[(size_t)w16 * 512 + (q & 15) * 32 + l31] = O[r];
    }
}

// ---- out projection (R11 pipelined version, unchanged): depth-1 pipeline,
// packed-B, cvt_pk; templated on CH for static indexing.
template <int CH>
__global__ __launch_bounds__(256) void out_proj(
    const float* __restrict__ pO, const float* __restrict__ pl,
    const ushort* __restrict__ Wot, const float* __restrict__ biasf,
    float* __restrict__ out)
{
    constexpr int chsh = (CH == 4) ? 2 : 1;
    int wave = threadIdx.x >> 6, lane = threadIdx.x & 63;
    int l16 = lane & 15, quad = lane >> 4;
    int m0 = (blockIdx.x >> 1) * 16;                  // grid = 512
    int n0 = (blockIdx.x & 1) * 256 + wave * 64;
    int row = m0 + l16;
    int bb = row >> 11, s = row & 2047;
    int qt = s >> 4, r16 = s & 15;

    auto loadP = [&](int ks, float4* u, float& lac) {
        int h = ks >> 5;
        int wid0 = (((bb * NH + h) << 7) + qt) << chsh;
        lac = 0.0f;
        #pragma unroll
        for (int cc = 0; cc < CH; ++cc) {
            const float* p = pO + ((size_t)(wid0 + cc) << 9) + r16 * 32 + quad * 8;
            u[cc * 2]     = *(const float4*)p;
            u[cc * 2 + 1] = *(const float4*)(p + 4);
            lac += pl[(wid0 + cc) * 16 + r16];
        }
    };
    auto loadB = [&](int ks, bf16x8* b) {
        #pragma unroll
        for (int j = 0; j < 4; ++j)
            b[j] = *(const bf16x8*)(Wot + (((size_t)((n0 >> 4) + j) * 32 + (ks >> 3) + quad) * 16 + l16) * 8);
    };

    f32x4 acc[4] = {};
    float4 uC[2 * CH], uN[2 * CH];
    float lacC, lacN;
    bf16x8 bC[4], bN[4];
    loadP(0, uC, lacC); loadB(0, bC);
    for (int ks = 0; ks < 256; ks += 32) {
        if (ks + 32 < 256) { loadP(ks + 32, uN, lacN); loadB(ks + 32, bN); }
        bf16x8 a;
        {
            float s8[8] = {0, 0, 0, 0, 0, 0, 0, 0};
            #pragma unroll
            for (int cc = 0; cc < CH; ++cc) {
                s8[0] += uC[cc * 2].x;     s8[1] += uC[cc * 2].y;
                s8[2] += uC[cc * 2].z;     s8[3] += uC[cc * 2].w;
                s8[4] += uC[cc * 2 + 1].x; s8[5] += uC[cc * 2 + 1].y;
                s8[6] += uC[cc * 2 + 1].z; s8[7] += uC[cc * 2 + 1].w;
            }
            float il = 1.0f / lacC;
            union { uint u[4]; bf16x8 v; } cv;
            cv.u[0] = cvt_pk_bf16(s8[0] * il, s8[1] * il);
            cv.u[1] = cvt_pk_bf16(s8[2] * il, s8[3] * il);
            cv.u[2] = cvt_pk_bf16(s8[4] * il, s8[5] * il);
            cv.u[3] = cvt_pk_bf16(s8[6] * il, s8[7] * il);
            a = cv.v;
        }
        #pragma unroll
        for (int j = 0; j < 4; ++j)
            acc[j] = MFMA(a, bC[j], acc[j], 0, 0, 0);
        #pragma unroll
        for (int i = 0; i < 2 * CH; ++i) uC[i] = uN[i];
        lacC = lacN;
        #pragma unroll
        for (int j = 0; j < 4; ++j) bC[j] = bN[j];
    }
    #pragma unroll
    for (int j = 0; j < 4; ++j) {
        int n = n0 + 16 * j + l16;
        float bs = biasf[768 + n];
        #pragma unroll
        for (int r = 0; r < 4; ++r)
            out[(size_t)(m0 + quad * 4 + r) * DM + n] = acc[j][r] + bs;
    }
}

extern "C" void kernel_launch(void* const* d_in, const int* in_sizes, int n_in,
                              void* d_out, int out_size, void* d_ws, size_t ws_size,
                              hipStream_t stream)
{
    const void* V    = d_in[0];
    const void* Q    = d_in[1];
    const void* K    = d_in[2];
    const void* mask = d_in[3];
    const void* Wq = d_in[4];  const void* bq = d_in[5];
    const void* Wk = d_in[6];  const void* bk = d_in[7];
    const void* Wv = d_in[8];  const void* bv = d_in[9];
    const void* Wo = d_in[10]; const void* bo = d_in[11];
    float* out = (float*)d_out;

    char* ws = (char*)d_ws;
    float*  biasf = (float*)ws;                    // 1280 fp32
    ushort* Wt  = (ushort*)(ws + 8192);            // 393,216 ushorts
    ushort* Wot = Wt  + 393216;                    // 131,072
    ushort* qh  = Wot + 131072;                    // 1,048,576 each (2 MB)
    ushort* kh  = qh  + 1048576;
    ushort* vT  = kh  + 1048576;
    float*  pO  = (float*)(vT + 1048576);          // [2048<<chsh][512] fp32
    int chsh = (ws_size >= 24649728u) ? 2 : 1;
    float*  pl  = pO + ((size_t)2048 << chsh) * 512;

    transpose_w<<<513, 256, 0, stream>>>(Wq, Wk, Wv, Wo, bq, bk, bv, bo,
                                         (const ushort*)Q, Wt, Wot, biasf);
    qkv_gemm<<<dim3(128, 3), 256, 0, stream>>>(Q, K, V, Wt, biasf, qh, kh, vT);
    attn<<<128 << chsh, 512, 0, stream>>>(qh, kh, vT, mask, pO, pl, chsh);
    if (chsh == 2)
        out_proj<4><<<512, 256, 0, stream>>>(pO, pl, Wot, biasf, out);
    else
        out_proj<2><<<512, 256, 0, stream>>>(pO, pl, Wot, biasf, out);
}